// Round 1
// baseline (329.101 us; speedup 1.0000x reference)
//
#include <hip/hip_runtime.h>
#include <math.h>

#define BATCH 128
#define DIM   8192
#define HW    49
#define PAIRS 2401          // 49*49
#define GSTRIDE 2512        // per-batch ws slot: 2401 G + 49 na + 49 nb (padded)
#define LPAD 132            // padded LDS row stride (floats): 132%32=4 -> conflict-free, 16B aligned

// ws float offsets
#define WS_MSE    0
#define WS_VARA   1
#define WS_VARB   2
#define WS_DIAGA  3
#define WS_DIAGB  4
#define WS_S1     5
#define WS_S2     6
#define WS_S3     7
#define WS_S4     8
#define WS_SK2A   9
#define WS_SK2B   10
#define GRAMA_OFF 16
#define GRAMB_OFF (16 + 16384)
#define LOCAL_OFF (16 + 32768)                  // 32784
#define ZERO_FLOATS (LOCAL_OFF + BATCH*GSTRIDE) // region that must be zeroed each launch
#define PART_OFF 360448
#define GK2_CHUNKS 64       // per tensor (KCH=128 each)

// ---------------------------------------------------------------------------
// L1: per-batch 49x49 feature dot products + row norms, K-split across blocks.
// grid = 128 batches * 8 splits, block = 256 (4 waves). Each wave takes a
// 32-float k-slice of the 128-float LDS stage; lanes 0..48 hold a 7x7 output
// tile (49 accumulators), lanes 49..62 compute the 98 row norms.
// ---------------------------------------------------------------------------
#define L1_SPLIT 8
#define L1_KCH (DIM / L1_SPLIT)   // 1024
#define L1_BK 128

__global__ __launch_bounds__(256) void l1_gram(const float* __restrict__ za,
                                               const float* __restrict__ zb,
                                               float* __restrict__ ws)
{
    __shared__ float smem[2 * HW * LPAD];   // 51.7 KB, reused as reduction scratch
    float* sa = smem;
    float* sb = smem + HW * LPAD;

    const int tid  = threadIdx.x;
    const int wave = tid >> 6;
    const int lane = tid & 63;
    const int batch = blockIdx.x / L1_SPLIT;
    const int kpart = blockIdx.x % L1_SPLIT;
    const float* Ab = za + (size_t)batch * HW * DIM + kpart * L1_KCH;
    const float* Bb = zb + (size_t)batch * HW * DIM + kpart * L1_KCH;

    float acc[49];
#pragma unroll
    for (int i = 0; i < 49; ++i) acc[i] = 0.f;

    const int ti = lane / 7, tj = lane % 7;

    for (int stage = 0; stage < L1_KCH / L1_BK; ++stage) {
        __syncthreads();
        // stage 49 x 128 floats of each tensor (1568 float4 each)
        for (int f = tid; f < HW * (L1_BK / 4); f += 256) {
            int row = f >> 5;            // f / 32
            int c4  = f & 31;
            const float4 va = *(const float4*)(Ab + (size_t)row * DIM + stage * L1_BK + c4 * 4);
            const float4 vb = *(const float4*)(Bb + (size_t)row * DIM + stage * L1_BK + c4 * 4);
            *(float4*)(sa + row * LPAD + c4 * 4) = va;
            *(float4*)(sb + row * LPAD + c4 * 4) = vb;
        }
        __syncthreads();
        const int kk0 = wave * 32;       // per-wave k-slice
        if (lane < 49) {
            for (int kk = kk0; kk < kk0 + 32; kk += 4) {
                float4 a4[7];
#pragma unroll
                for (int p = 0; p < 7; ++p)
                    a4[p] = *(const float4*)(sa + (ti * 7 + p) * LPAD + kk);
#pragma unroll
                for (int q = 0; q < 7; ++q) {
                    float4 b4 = *(const float4*)(sb + (tj * 7 + q) * LPAD + kk);
#pragma unroll
                    for (int p = 0; p < 7; ++p)
                        acc[p * 7 + q] += a4[p].x * b4.x + a4[p].y * b4.y
                                        + a4[p].z * b4.z + a4[p].w * b4.w;
                }
            }
        } else if (lane < 63) {
            const int r0 = lane - 49;                 // 0..6 -> za norms, 7..13 -> zb norms
            const float* S = (r0 < 7) ? sa : sb;
            const int g = (r0 < 7) ? r0 : r0 - 7;
            for (int kk = kk0; kk < kk0 + 32; kk += 4) {
#pragma unroll
                for (int r = 0; r < 7; ++r) {
                    float4 v = *(const float4*)(S + (g * 7 + r) * LPAD + kk);
                    acc[r] += v.x * v.x + v.y * v.y + v.z * v.z + v.w * v.w;
                }
            }
        }
    }
    // block-level merge in LDS, then one atomic flush per element
    __syncthreads();
    for (int i = tid; i < 2499; i += 256) smem[i] = 0.f;
    __syncthreads();
    if (lane < 49) {
#pragma unroll
        for (int p = 0; p < 7; ++p)
#pragma unroll
            for (int q = 0; q < 7; ++q)
                atomicAdd(&smem[(ti * 7 + p) * 49 + (tj * 7 + q)], acc[p * 7 + q]);
    } else if (lane < 63) {
        const int r0 = lane - 49;
        const int base = PAIRS + (r0 < 7 ? 0 : 49) + (r0 < 7 ? r0 : r0 - 7) * 7;
#pragma unroll
        for (int r = 0; r < 7; ++r) atomicAdd(&smem[base + r], acc[r]);
    }
    __syncthreads();
    float* gout = ws + LOCAL_OFF + (size_t)batch * GSTRIDE;
    for (int i = tid; i < 2499; i += 256) atomicAdd(&gout[i], smem[i]);
}

// ---------------------------------------------------------------------------
// L2: per-batch matching. Builds d2f (feature) and d2g (grid) 49x49 in LDS,
// does argmin rows/cols (first-occurrence) + stable rank top-k selection,
// accumulates the four selected-d2 sums. mse == sum(selected d2)/norm.
// ---------------------------------------------------------------------------
__global__ __launch_bounds__(256) void l2_match(const float* __restrict__ ga,
                                                const float* __restrict__ gb,
                                                float* __restrict__ ws)
{
    __shared__ float d2f[PAIRS];
    __shared__ float d2g[PAIRS];
    __shared__ float nA[49], nB[49];
    __shared__ float gax[49], gay[49], gbx[49], gby[49];
    __shared__ float mval[4][49];
    __shared__ int   midx[4][49];

    const int tid = threadIdx.x;
    const int batch = blockIdx.x;
    const float* Gt = ws + LOCAL_OFF + (size_t)batch * GSTRIDE;

    if (tid < 49) nA[tid] = Gt[PAIRS + tid];
    else if (tid >= 64 && tid < 113) nB[tid - 64] = Gt[PAIRS + 49 + (tid - 64)];
    if (tid >= 128 && tid < 177) {
        int i = tid - 128;
        gax[i] = ga[batch * 98 + i * 2];
        gay[i] = ga[batch * 98 + i * 2 + 1];
    } else if (tid >= 192 && tid < 241) {
        int i = tid - 192;
        gbx[i] = gb[batch * 98 + i * 2];
        gby[i] = gb[batch * 98 + i * 2 + 1];
    }
    __syncthreads();
    for (int e = tid; e < PAIRS; e += 256) {
        int i = e / 49, j = e - i * 49;
        d2f[e] = nA[i] + nB[j] - 2.0f * Gt[e];
        float dx = gax[i] - gbx[j], dy = gay[i] - gby[j];
        d2g[e] = dx * dx + dy * dy;
    }
    __syncthreads();
    const int task = tid >> 6, l = tid & 63;
    if (l < 49) {
        float bv = 3.0e38f; int bi = 0;
        if (task == 0) {        // feature a->b: row mins
            for (int j = 0; j < 49; ++j) { float v = d2f[l * 49 + j]; if (v < bv) { bv = v; bi = j; } }
        } else if (task == 1) { // feature b->a: col mins
            for (int i = 0; i < 49; ++i) { float v = d2f[i * 49 + l]; if (v < bv) { bv = v; bi = i; } }
        } else if (task == 2) { // grid a->b: row mins
            for (int j = 0; j < 49; ++j) { float v = d2g[l * 49 + j]; if (v < bv) { bv = v; bi = j; } }
        } else {                // grid b->a: col mins
            for (int i = 0; i < 49; ++i) { float v = d2g[i * 49 + l]; if (v < bv) { bv = v; bi = i; } }
        }
        mval[task][l] = bv; midx[task][l] = bi;
    }
    __syncthreads();
    if (l < 49) {
        float v = mval[task][l];
        int rank = 0;
        for (int k = 0; k < 49; ++k) {
            float u = mval[task][k];
            rank += (u < v) || (u == v && k < l);   // stable, matches lax.top_k ties
        }
        if (task == 0)      { if (rank < 20) atomicAdd(&ws[WS_S1], v); }
        else if (task == 1) { if (rank < 20) atomicAdd(&ws[WS_S2], v); }
        else if (task == 2) { if (rank < 20) atomicAdd(&ws[WS_S3], d2f[l * 49 + midx[2][l]]); }
        else                { if (rank < 4)  atomicAdd(&ws[WS_S4], d2f[midx[3][l] * 49 + l]); }
    }
}

// ---------------------------------------------------------------------------
// GK1: column stats of z_a / z_b (mean, centered sumsq) + global MSE.
// 32 blocks x 256 threads, one column per thread, coalesced row loop.
// ---------------------------------------------------------------------------
__global__ __launch_bounds__(256) void gk1_colstats(const float* __restrict__ za,
                                                    const float* __restrict__ zb,
                                                    float* __restrict__ ws)
{
    const int c = blockIdx.x * 256 + threadIdx.x;
    float sa = 0.f, qa = 0.f, sb = 0.f, qb = 0.f, ms = 0.f;
    for (int r = 0; r < BATCH; ++r) {
        float a = za[(size_t)r * DIM + c];
        float b = zb[(size_t)r * DIM + c];
        sa += a; qa += a * a;
        sb += b; qb += b * b;
        float d = a - b; ms += d * d;
    }
    float sA = qa - sa * sa * (1.0f / BATCH);     // sum (x-m)^2
    float sB = qb - sb * sb * (1.0f / BATCH);
    float stdA = sqrtf(sA * (1.0f / (BATCH - 1)) + 1e-4f);
    float stdB = sqrtf(sB * (1.0f / (BATCH - 1)) + 1e-4f);
    float rA = fmaxf(0.f, 1.f - stdA);
    float rB = fmaxf(0.f, 1.f - stdB);
    float dA = sA * sA, dB = sB * sB;
    for (int o = 32; o; o >>= 1) {
        ms += __shfl_xor(ms, o);
        rA += __shfl_xor(rA, o);
        rB += __shfl_xor(rB, o);
        dA += __shfl_xor(dA, o);
        dB += __shfl_xor(dB, o);
    }
    if ((threadIdx.x & 63) == 0) {
        atomicAdd(&ws[WS_MSE],   ms);
        atomicAdd(&ws[WS_VARA],  rA);
        atomicAdd(&ws[WS_VARB],  rB);
        atomicAdd(&ws[WS_DIAGA], dA);
        atomicAdd(&ws[WS_DIAGB], dB);
    }
}

// ---------------------------------------------------------------------------
// GK2: 128x128 Gram G = X X^T per tensor, K-split (KCH=128, 2 stages of 64).
// 16x16 threads, 8x8 per-thread tile with stride-16 row mapping (bank-clean).
// Writes disjoint partials (no atomics); GK2R reduces them.
// ---------------------------------------------------------------------------
#define GK2_BK 64
#define GK2_KCH 128
#define GK2_PAD 68

__global__ __launch_bounds__(256) void gk2_gram(const float* __restrict__ za,
                                                const float* __restrict__ zb,
                                                float* __restrict__ ws)
{
    __shared__ float sx[128 * GK2_PAD];   // 34.8 KB
    const int tid = threadIdx.x;
    const int tensor = blockIdx.x / GK2_CHUNKS;
    const int chunk  = blockIdx.x % GK2_CHUNKS;
    const float* X = (tensor ? zb : za) + chunk * GK2_KCH;
    const int ty = tid / 16, tx = tid % 16;

    float acc[8][8];
#pragma unroll
    for (int r = 0; r < 8; ++r)
#pragma unroll
        for (int c = 0; c < 8; ++c) acc[r][c] = 0.f;

    for (int stage = 0; stage < 2; ++stage) {
        __syncthreads();
        for (int f = tid; f < 128 * (GK2_BK / 4); f += 256) {
            int row = f >> 4;          // f / 16
            int c4  = f & 15;
            *(float4*)(sx + row * GK2_PAD + c4 * 4) =
                *(const float4*)(X + (size_t)row * DIM + stage * GK2_BK + c4 * 4);
        }
        __syncthreads();
        for (int k = 0; k < GK2_BK; k += 4) {
            float4 a4[8];
#pragma unroll
            for (int r = 0; r < 8; ++r) a4[r] = *(const float4*)(sx + (ty + 16 * r) * GK2_PAD + k);
#pragma unroll
            for (int c = 0; c < 8; ++c) {
                float4 b4 = *(const float4*)(sx + (tx + 16 * c) * GK2_PAD + k);
#pragma unroll
                for (int r = 0; r < 8; ++r)
                    acc[r][c] += a4[r].x * b4.x + a4[r].y * b4.y + a4[r].z * b4.z + a4[r].w * b4.w;
            }
        }
    }
    float* P = ws + PART_OFF + (size_t)blockIdx.x * 16384;
#pragma unroll
    for (int r = 0; r < 8; ++r)
#pragma unroll
        for (int c = 0; c < 8; ++c)
            P[(ty + 16 * r) * 128 + (tx + 16 * c)] = acc[r][c];
}

__global__ __launch_bounds__(256) void gk2_reduce(float* __restrict__ ws)
{
    const int g = blockIdx.x * 256 + threadIdx.x;   // 0..32767
    const int tensor = g >> 14;
    const int e = g & 16383;
    const float* P = ws + PART_OFF + (size_t)tensor * GK2_CHUNKS * 16384;
    float s = 0.f;
    for (int c = 0; c < GK2_CHUNKS; ++c) s += P[(size_t)c * 16384 + e];
    ws[(tensor ? GRAMB_OFF : GRAMA_OFF) + e] = s;
}

// ---------------------------------------------------------------------------
// GK3: ||K||_F^2 from the Gram matrix. K = G - (r_a+r_b)/n + S/n^2.
// Uses col sums (== row sums, G symmetric) for coalesced access.
// ---------------------------------------------------------------------------
__global__ __launch_bounds__(256) void gk3_cov(float* __restrict__ ws)
{
    __shared__ float r[128];
    __shared__ float sS;
    __shared__ float wr[4];
    const int tid = threadIdx.x;
    const float* G = ws + (blockIdx.x ? GRAMB_OFF : GRAMA_OFF);
    if (tid < 128) {
        float s = 0.f;
        for (int k = 0; k < 128; ++k) s += G[k * 128 + tid];
        r[tid] = s;
    }
    __syncthreads();
    if (tid < 64) {
        float t = r[tid] + r[tid + 64];
        for (int o = 32; o; o >>= 1) t += __shfl_xor(t, o);
        if (tid == 0) sS = t;
    }
    __syncthreads();
    const float S = sS;
    float sk = 0.f;
    for (int e = tid; e < 16384; e += 256) {
        float K = G[e] - (r[e >> 7] + r[e & 127]) * (1.0f / 128.0f) + S * (1.0f / 16384.0f);
        sk += K * K;
    }
    for (int o = 32; o; o >>= 1) sk += __shfl_xor(sk, o);
    if ((tid & 63) == 0) wr[tid >> 6] = sk;
    __syncthreads();
    if (tid == 0)
        ws[blockIdx.x ? WS_SK2B : WS_SK2A] = wr[0] + wr[1] + wr[2] + wr[3];
}

// ---------------------------------------------------------------------------
// GK4: final scalar assembly.
// ---------------------------------------------------------------------------
__global__ void gk4_final(const float* __restrict__ ws, float* __restrict__ out)
{
    if (threadIdx.x == 0) {
        float inv_g = ws[WS_MSE] * (1.0f / ((float)BATCH * (float)DIM));
        float varl  = 0.5f * (ws[WS_VARA] + ws[WS_VARB]) * (1.0f / (float)DIM);
        float cov   = (ws[WS_SK2A] - ws[WS_DIAGA] + ws[WS_SK2B] - ws[WS_DIAGB])
                      * (1.0f / (127.0f * 127.0f * (float)DIM));
        float gl = 25.0f * inv_g + 25.0f * varl + cov;
        float m20 = (float)BATCH * 20.0f * (float)DIM;
        float m4  = (float)BATCH * 4.0f  * (float)DIM;
        float invl = 0.5f * (ws[WS_S1] + ws[WS_S2] + ws[WS_S3]) / m20
                   + 0.5f * ws[WS_S4] / m4;
        out[0] = 0.25f * gl + 0.75f * (25.0f * invl);
    }
}

extern "C" void kernel_launch(void* const* d_in, const int* in_sizes, int n_in,
                              void* d_out, int out_size, void* d_ws, size_t ws_size,
                              hipStream_t stream)
{
    (void)in_sizes; (void)n_in; (void)out_size; (void)ws_size;
    const float* z_a = (const float*)d_in[0];
    const float* z_b = (const float*)d_in[1];
    const float* zla = (const float*)d_in[2];
    const float* zlb = (const float*)d_in[3];
    const float* ga  = (const float*)d_in[4];
    const float* gb  = (const float*)d_in[5];
    float* ws  = (float*)d_ws;
    float* out = (float*)d_out;

    hipMemsetAsync(d_ws, 0, (size_t)ZERO_FLOATS * sizeof(float), stream);
    l1_gram<<<BATCH * L1_SPLIT, 256, 0, stream>>>(zla, zlb, ws);
    gk1_colstats<<<DIM / 256, 256, 0, stream>>>(z_a, z_b, ws);
    gk2_gram<<<2 * GK2_CHUNKS, 256, 0, stream>>>(z_a, z_b, ws);
    gk2_reduce<<<32768 / 256, 256, 0, stream>>>(ws);
    l2_match<<<BATCH, 256, 0, stream>>>(ga, gb, ws);
    gk3_cov<<<2, 256, 0, stream>>>(ws);
    gk4_final<<<1, 64, 0, stream>>>(ws, out);
}

// Round 2
// 220.624 us; speedup vs baseline: 1.4917x; 1.4917x over previous
//
#include <hip/hip_runtime.h>
#include <math.h>

#define BATCH 128
#define DIM   8192
#define HW    49
#define PAIRS 2401          // 49*49
#define GSTRIDE 2512        // per-batch ws slot: 2401 G + 49 na + 49 nb (padded)

// ws float offsets
#define WS_MSE    0
#define WS_VARA   1
#define WS_VARB   2
#define WS_DIAGA  3
#define WS_DIAGB  4
#define WS_S1     5
#define WS_S2     6
#define WS_S3     7
#define WS_S4     8
#define WS_SK2A   9
#define WS_SK2B   10
#define GRAMA_OFF 16
#define GRAMB_OFF (16 + 16384)
#define LOCAL_OFF (16 + 32768)                       // 32784
#define COLS_OFF  (LOCAL_OFF + BATCH * GSTRIDE)      // 354320: sa,qa,sb,qb col arrays
#define ZERO_FLOATS (COLS_OFF + 4 * DIM)             // 387088 floats (~1.5 MB memset)

typedef __attribute__((ext_vector_type(8))) short bf16x8;
typedef __attribute__((ext_vector_type(4))) float f32x4;

__device__ __forceinline__ unsigned pk2bf(float lo, float hi) {
    unsigned ulo = __float_as_uint(lo);
    unsigned uhi = __float_as_uint(hi);
    ulo += 0x7FFFu + ((ulo >> 16) & 1u);   // RNE to bf16
    uhi += 0x7FFFu + ((uhi >> 16) & 1u);
    return (ulo >> 16) | (uhi & 0xFFFF0000u);
}
__device__ __forceinline__ float sq4(float4 v) {
    return v.x * v.x + v.y * v.y + v.z * v.z + v.w * v.w;
}

// ---------------------------------------------------------------------------
// L1: per-batch padded 64x64 Gram of the 49x8192 feature maps via bf16 MFMA.
// grid = 128 batches * 8 K-splits (K=1024/block), block = 256 (4 waves).
// Stage BK=128: reg-stage fp32 (coalesced 32B/thread), cvt->bf16, ds_write to
// XOR-swizzled [64][128] bf16 tiles; each wave computes a 32x32 quadrant with
// 16x16x32 MFMA (frag: row=lane&15, k=(lane>>4)*8+e; C/D: col=lane&15,
// row=(lane>>4)*4+reg). fp32 row norms from the staged regs. atomicAdd out.
// ---------------------------------------------------------------------------
#define L1_SPLIT 8
#define L1_KB 1024
#define L1_BK 128
#define L1_STAGES (L1_KB / L1_BK)   // 8

__device__ __forceinline__ void l1_mfma_step(const unsigned char* lds, int r0, int c0,
                                             int kg16, int fsw, f32x4 acc[2][2])
{
#pragma unroll
    for (int kk2 = 0; kk2 < 256; kk2 += 64) {        // kk*2 bytes, kk = 0,32,64,96
        const bf16x8 a0 = *(const bf16x8*)(lds + ((r0 * 256 + kk2 + kg16) ^ fsw));
        const bf16x8 a1 = *(const bf16x8*)(lds + (((r0 + 16) * 256 + kk2 + kg16) ^ fsw));
        const bf16x8 b0 = *(const bf16x8*)(lds + 16384 + ((c0 * 256 + kk2 + kg16) ^ fsw));
        const bf16x8 b1 = *(const bf16x8*)(lds + 16384 + (((c0 + 16) * 256 + kk2 + kg16) ^ fsw));
        acc[0][0] = __builtin_amdgcn_mfma_f32_16x16x32_bf16(a0, b0, acc[0][0], 0, 0, 0);
        acc[0][1] = __builtin_amdgcn_mfma_f32_16x16x32_bf16(a0, b1, acc[0][1], 0, 0, 0);
        acc[1][0] = __builtin_amdgcn_mfma_f32_16x16x32_bf16(a1, b0, acc[1][0], 0, 0, 0);
        acc[1][1] = __builtin_amdgcn_mfma_f32_16x16x32_bf16(a1, b1, acc[1][1], 0, 0, 0);
    }
}

__global__ __launch_bounds__(256, 4) void l1_gram(const float* __restrict__ za,
                                                  const float* __restrict__ zb,
                                                  float* __restrict__ ws)
{
    __shared__ unsigned char lds[32768];   // [2 tensors][64 rows][128 bf16], swizzled

    const int tid = threadIdx.x;
    const int batch = blockIdx.x / L1_SPLIT;
    const int ks    = blockIdx.x % L1_SPLIT;
    const float* Ab = za + (size_t)batch * HW * DIM + ks * L1_KB;
    const float* Bb = zb + (size_t)batch * HW * DIM + ks * L1_KB;

    const int c8 = tid & 15;            // 16B chunk within row
    const int rb = tid >> 4;            // base row 0..15
    const int lane = tid & 63;
    const int wv = tid >> 6;
    const int wr = wv >> 1, wc = wv & 1;
    const int kg = lane >> 4, fr = lane & 15;
    const int kg16 = kg * 16;
    const int fsw = (fr & 7) << 4;      // fragment-read swizzle (row&7 == fr&7)
    const int ssw = (rb & 7) << 4;      // staging-write swizzle (row&7 == rb&7)
    const int r0 = wr * 32 + fr;
    const int c0 = wc * 32 + fr;

    const float* gA = Ab + (size_t)rb * DIM + (size_t)(c8 * 8);
    const float* gB = Bb + (size_t)rb * DIM + (size_t)(c8 * 8);

    // zero pad rows 49..63 once (never rewritten; swizzle maps within-row)
    for (int i = tid; i < 480; i += 256) {
        int tens = (i >= 240);
        int j = i - tens * 240;
        *(uint4*)(lds + tens * 16384 + (49 + (j >> 4)) * 256 + (j & 15) * 16) =
            make_uint4(0u, 0u, 0u, 0u);
    }

    f32x4 acc[2][2];
    const f32x4 z4 = {0.f, 0.f, 0.f, 0.f};
    acc[0][0] = z4; acc[0][1] = z4; acc[1][0] = z4; acc[1][1] = z4;
    float nA[4] = {0.f, 0.f, 0.f, 0.f}, nB[4] = {0.f, 0.f, 0.f, 0.f};
    float4 va[4][2], vb[4][2];

    auto load_stage = [&](int t) {
#pragma unroll
        for (int p = 0; p < 4; ++p) {
            if (rb + 16 * p < HW) {
                const float* pa = gA + (size_t)t * L1_BK + (size_t)(p * 16) * DIM;
                const float* pb = gB + (size_t)t * L1_BK + (size_t)(p * 16) * DIM;
                va[p][0] = *(const float4*)pa;
                va[p][1] = *(const float4*)(pa + 4);
                vb[p][0] = *(const float4*)pb;
                vb[p][1] = *(const float4*)(pb + 4);
            }
        }
    };
    auto write_stage = [&]() {
#pragma unroll
        for (int p = 0; p < 4; ++p) {
            if (rb + 16 * p < HW) {
                const int ab = (((rb + 16 * p) * 256) + c8 * 16) ^ ssw;
                uint4 wA, wB;
                wA.x = pk2bf(va[p][0].x, va[p][0].y);
                wA.y = pk2bf(va[p][0].z, va[p][0].w);
                wA.z = pk2bf(va[p][1].x, va[p][1].y);
                wA.w = pk2bf(va[p][1].z, va[p][1].w);
                wB.x = pk2bf(vb[p][0].x, vb[p][0].y);
                wB.y = pk2bf(vb[p][0].z, vb[p][0].w);
                wB.z = pk2bf(vb[p][1].x, vb[p][1].y);
                wB.w = pk2bf(vb[p][1].z, vb[p][1].w);
                *(uint4*)(lds + ab) = wA;
                *(uint4*)(lds + 16384 + ab) = wB;
                nA[p] += sq4(va[p][0]) + sq4(va[p][1]);
                nB[p] += sq4(vb[p][0]) + sq4(vb[p][1]);
            }
        }
    };

    load_stage(0);
    write_stage();
    __syncthreads();
    for (int t = 1; t < L1_STAGES; ++t) {
        load_stage(t);                       // overlap next-stage loads with MFMA
        l1_mfma_step(lds, r0, c0, kg16, fsw, acc);
        __syncthreads();                     // MFMA readers done
        write_stage();                       // vmcnt wait lands here
        __syncthreads();                     // tile visible
    }
    l1_mfma_step(lds, r0, c0, kg16, fsw, acc);

    float* gout = ws + LOCAL_OFF + (size_t)batch * GSTRIDE;

    // row norms: 16 threads per row (consecutive lanes), shfl tree then atomic
#pragma unroll
    for (int p = 0; p < 4; ++p) {
        float vA = nA[p], vB = nB[p];
        vA += __shfl_xor(vA, 1);  vB += __shfl_xor(vB, 1);
        vA += __shfl_xor(vA, 2);  vB += __shfl_xor(vB, 2);
        vA += __shfl_xor(vA, 4);  vB += __shfl_xor(vB, 4);
        vA += __shfl_xor(vA, 8);  vB += __shfl_xor(vB, 8);
        int row = rb + 16 * p;
        if ((tid & 15) == 0 && row < HW) {
            atomicAdd(&gout[PAIRS + row], vA);
            atomicAdd(&gout[PAIRS + HW + row], vB);
        }
    }

    // Gram writeout: C/D layout col=lane&15, row=(lane>>4)*4+reg
#pragma unroll
    for (int sr = 0; sr < 2; ++sr)
#pragma unroll
        for (int sc = 0; sc < 2; ++sc)
#pragma unroll
            for (int r = 0; r < 4; ++r) {
                int row = wr * 32 + sr * 16 + kg * 4 + r;
                int col = wc * 32 + sc * 16 + fr;
                if (row < HW && col < HW)
                    atomicAdd(&gout[row * HW + col], acc[sr][sc][r]);
            }
}

// ---------------------------------------------------------------------------
// L2: per-batch matching (unchanged from passing round).
// ---------------------------------------------------------------------------
__global__ __launch_bounds__(256) void l2_match(const float* __restrict__ ga,
                                                const float* __restrict__ gb,
                                                float* __restrict__ ws)
{
    __shared__ float d2f[PAIRS];
    __shared__ float d2g[PAIRS];
    __shared__ float nA[49], nB[49];
    __shared__ float gax[49], gay[49], gbx[49], gby[49];
    __shared__ float mval[4][49];
    __shared__ int   midx[4][49];

    const int tid = threadIdx.x;
    const int batch = blockIdx.x;
    const float* Gt = ws + LOCAL_OFF + (size_t)batch * GSTRIDE;

    if (tid < 49) nA[tid] = Gt[PAIRS + tid];
    else if (tid >= 64 && tid < 113) nB[tid - 64] = Gt[PAIRS + 49 + (tid - 64)];
    if (tid >= 128 && tid < 177) {
        int i = tid - 128;
        gax[i] = ga[batch * 98 + i * 2];
        gay[i] = ga[batch * 98 + i * 2 + 1];
    } else if (tid >= 192 && tid < 241) {
        int i = tid - 192;
        gbx[i] = gb[batch * 98 + i * 2];
        gby[i] = gb[batch * 98 + i * 2 + 1];
    }
    __syncthreads();
    for (int e = tid; e < PAIRS; e += 256) {
        int i = e / 49, j = e - i * 49;
        d2f[e] = nA[i] + nB[j] - 2.0f * Gt[e];
        float dx = gax[i] - gbx[j], dy = gay[i] - gby[j];
        d2g[e] = dx * dx + dy * dy;
    }
    __syncthreads();
    const int task = tid >> 6, l = tid & 63;
    if (l < 49) {
        float bv = 3.0e38f; int bi = 0;
        if (task == 0) {
            for (int j = 0; j < 49; ++j) { float v = d2f[l * 49 + j]; if (v < bv) { bv = v; bi = j; } }
        } else if (task == 1) {
            for (int i = 0; i < 49; ++i) { float v = d2f[i * 49 + l]; if (v < bv) { bv = v; bi = i; } }
        } else if (task == 2) {
            for (int j = 0; j < 49; ++j) { float v = d2g[l * 49 + j]; if (v < bv) { bv = v; bi = j; } }
        } else {
            for (int i = 0; i < 49; ++i) { float v = d2g[i * 49 + l]; if (v < bv) { bv = v; bi = i; } }
        }
        mval[task][l] = bv; midx[task][l] = bi;
    }
    __syncthreads();
    if (l < 49) {
        float v = mval[task][l];
        int rank = 0;
        for (int k = 0; k < 49; ++k) {
            float u = mval[task][k];
            rank += (u < v) || (u == v && k < l);
        }
        if (task == 0)      { if (rank < 20) atomicAdd(&ws[WS_S1], v); }
        else if (task == 1) { if (rank < 20) atomicAdd(&ws[WS_S2], v); }
        else if (task == 2) { if (rank < 20) atomicAdd(&ws[WS_S3], d2f[l * 49 + midx[2][l]]); }
        else                { if (rank < 4)  atomicAdd(&ws[WS_S4], d2f[midx[3][l] * 49 + l]); }
    }
}

// ---------------------------------------------------------------------------
// GK1a: row-split column partial sums (256 blocks -> enough loads in flight).
// block b: cols [(b&31)*256, +256), rows [(b>>5)*16, +16).
// ---------------------------------------------------------------------------
__global__ __launch_bounds__(256) void gk1a(const float* __restrict__ za,
                                            const float* __restrict__ zb,
                                            float* __restrict__ ws)
{
    const int col = (blockIdx.x & 31) * 256 + threadIdx.x;
    const int rg  = blockIdx.x >> 5;
    const float* A = za + (size_t)(rg * 16) * DIM + col;
    const float* B = zb + (size_t)(rg * 16) * DIM + col;
    float sa = 0.f, qa = 0.f, sb = 0.f, qb = 0.f, ms = 0.f;
#pragma unroll
    for (int r = 0; r < 16; ++r) {
        float a = A[(size_t)r * DIM];
        float b = B[(size_t)r * DIM];
        sa += a; qa += a * a;
        sb += b; qb += b * b;
        float d = a - b; ms += d * d;
    }
    atomicAdd(&ws[COLS_OFF + col], sa);
    atomicAdd(&ws[COLS_OFF + DIM + col], qa);
    atomicAdd(&ws[COLS_OFF + 2 * DIM + col], sb);
    atomicAdd(&ws[COLS_OFF + 3 * DIM + col], qb);
    for (int o = 32; o; o >>= 1) ms += __shfl_xor(ms, o);
    if ((threadIdx.x & 63) == 0) atomicAdd(&ws[WS_MSE], ms);
}

// GK1b: per-column std/relu/diag from the col arrays, reduce to scalars.
__global__ __launch_bounds__(256) void gk1b(float* __restrict__ ws)
{
    const int col = blockIdx.x * 256 + threadIdx.x;
    float sa = ws[COLS_OFF + col];
    float qa = ws[COLS_OFF + DIM + col];
    float sb = ws[COLS_OFF + 2 * DIM + col];
    float qb = ws[COLS_OFF + 3 * DIM + col];
    float sA = qa - sa * sa * (1.0f / BATCH);
    float sB = qb - sb * sb * (1.0f / BATCH);
    float rA = fmaxf(0.f, 1.f - sqrtf(sA * (1.0f / (BATCH - 1)) + 1e-4f));
    float rB = fmaxf(0.f, 1.f - sqrtf(sB * (1.0f / (BATCH - 1)) + 1e-4f));
    float dA = sA * sA, dB = sB * sB;
    for (int o = 32; o; o >>= 1) {
        rA += __shfl_xor(rA, o);
        rB += __shfl_xor(rB, o);
        dA += __shfl_xor(dA, o);
        dB += __shfl_xor(dB, o);
    }
    if ((threadIdx.x & 63) == 0) {
        atomicAdd(&ws[WS_VARA],  rA);
        atomicAdd(&ws[WS_VARB],  rB);
        atomicAdd(&ws[WS_DIAGA], dA);
        atomicAdd(&ws[WS_DIAGB], dB);
    }
}

// ---------------------------------------------------------------------------
// GK2: 128x128 Gram of z_a / z_b, K-split 64 chunks, direct L2 atomics out.
// ---------------------------------------------------------------------------
#define GK2_BK 64
#define GK2_KCH 128
#define GK2_PAD 68
#define GK2_CHUNKS 64

__global__ __launch_bounds__(256) void gk2_gram(const float* __restrict__ za,
                                                const float* __restrict__ zb,
                                                float* __restrict__ ws)
{
    __shared__ float sx[128 * GK2_PAD];
    const int tid = threadIdx.x;
    const int tensor = blockIdx.x / GK2_CHUNKS;
    const int chunk  = blockIdx.x % GK2_CHUNKS;
    const float* X = (tensor ? zb : za) + chunk * GK2_KCH;
    const int ty = tid / 16, tx = tid % 16;

    float acc[8][8];
#pragma unroll
    for (int r = 0; r < 8; ++r)
#pragma unroll
        for (int c = 0; c < 8; ++c) acc[r][c] = 0.f;

    for (int stage = 0; stage < 2; ++stage) {
        __syncthreads();
        for (int f = tid; f < 128 * (GK2_BK / 4); f += 256) {
            int row = f >> 4;
            int c4  = f & 15;
            *(float4*)(sx + row * GK2_PAD + c4 * 4) =
                *(const float4*)(X + (size_t)row * DIM + stage * GK2_BK + c4 * 4);
        }
        __syncthreads();
        for (int k = 0; k < GK2_BK; k += 4) {
            float4 a4[8];
#pragma unroll
            for (int r = 0; r < 8; ++r) a4[r] = *(const float4*)(sx + (ty + 16 * r) * GK2_PAD + k);
#pragma unroll
            for (int c = 0; c < 8; ++c) {
                float4 b4 = *(const float4*)(sx + (tx + 16 * c) * GK2_PAD + k);
#pragma unroll
                for (int r = 0; r < 8; ++r)
                    acc[r][c] += a4[r].x * b4.x + a4[r].y * b4.y + a4[r].z * b4.z + a4[r].w * b4.w;
            }
        }
    }
    float* G = ws + (tensor ? GRAMB_OFF : GRAMA_OFF);
#pragma unroll
    for (int r = 0; r < 8; ++r)
#pragma unroll
        for (int c = 0; c < 8; ++c)
            atomicAdd(&G[(ty + 16 * r) * 128 + (tx + 16 * c)], acc[r][c]);
}

// ---------------------------------------------------------------------------
// GK3: ||K||_F^2 from the Gram matrix (unchanged math, unrolled row-sums).
// ---------------------------------------------------------------------------
__global__ __launch_bounds__(256) void gk3_cov(float* __restrict__ ws)
{
    __shared__ float r[128];
    __shared__ float sS;
    __shared__ float wr[4];
    const int tid = threadIdx.x;
    const float* G = ws + (blockIdx.x ? GRAMB_OFF : GRAMA_OFF);
    if (tid < 128) {
        float s0 = 0.f, s1 = 0.f, s2 = 0.f, s3 = 0.f;
        for (int k = 0; k < 128; k += 4) {
            s0 += G[(k + 0) * 128 + tid];
            s1 += G[(k + 1) * 128 + tid];
            s2 += G[(k + 2) * 128 + tid];
            s3 += G[(k + 3) * 128 + tid];
        }
        r[tid] = (s0 + s1) + (s2 + s3);
    }
    __syncthreads();
    if (tid < 64) {
        float t = r[tid] + r[tid + 64];
        for (int o = 32; o; o >>= 1) t += __shfl_xor(t, o);
        if (tid == 0) sS = t;
    }
    __syncthreads();
    const float S = sS;
    float sk = 0.f;
    for (int e = tid; e < 16384; e += 256) {
        float K = G[e] - (r[e >> 7] + r[e & 127]) * (1.0f / 128.0f) + S * (1.0f / 16384.0f);
        sk += K * K;
    }
    for (int o = 32; o; o >>= 1) sk += __shfl_xor(sk, o);
    if ((tid & 63) == 0) wr[tid >> 6] = sk;
    __syncthreads();
    if (tid == 0)
        ws[blockIdx.x ? WS_SK2B : WS_SK2A] = wr[0] + wr[1] + wr[2] + wr[3];
}

// ---------------------------------------------------------------------------
// GK4: final scalar assembly.
// ---------------------------------------------------------------------------
__global__ void gk4_final(const float* __restrict__ ws, float* __restrict__ out)
{
    if (threadIdx.x == 0) {
        float inv_g = ws[WS_MSE] * (1.0f / ((float)BATCH * (float)DIM));
        float varl  = 0.5f * (ws[WS_VARA] + ws[WS_VARB]) * (1.0f / (float)DIM);
        float cov   = (ws[WS_SK2A] - ws[WS_DIAGA] + ws[WS_SK2B] - ws[WS_DIAGB])
                      * (1.0f / (127.0f * 127.0f * (float)DIM));
        float gl = 25.0f * inv_g + 25.0f * varl + cov;
        float m20 = (float)BATCH * 20.0f * (float)DIM;
        float m4  = (float)BATCH * 4.0f  * (float)DIM;
        float invl = 0.5f * (ws[WS_S1] + ws[WS_S2] + ws[WS_S3]) / m20
                   + 0.5f * ws[WS_S4] / m4;
        out[0] = 0.25f * gl + 0.75f * (25.0f * invl);
    }
}

extern "C" void kernel_launch(void* const* d_in, const int* in_sizes, int n_in,
                              void* d_out, int out_size, void* d_ws, size_t ws_size,
                              hipStream_t stream)
{
    (void)in_sizes; (void)n_in; (void)out_size; (void)ws_size;
    const float* z_a = (const float*)d_in[0];
    const float* z_b = (const float*)d_in[1];
    const float* zla = (const float*)d_in[2];
    const float* zlb = (const float*)d_in[3];
    const float* ga  = (const float*)d_in[4];
    const float* gb  = (const float*)d_in[5];
    float* ws  = (float*)d_ws;
    float* out = (float*)d_out;

    hipMemsetAsync(d_ws, 0, (size_t)ZERO_FLOATS * sizeof(float), stream);
    l1_gram<<<BATCH * L1_SPLIT, 256, 0, stream>>>(zla, zlb, ws);
    gk1a<<<256, 256, 0, stream>>>(z_a, z_b, ws);
    gk2_gram<<<2 * GK2_CHUNKS, 256, 0, stream>>>(z_a, z_b, ws);
    gk1b<<<DIM / 256, 256, 0, stream>>>(ws);
    l2_match<<<BATCH, 256, 0, stream>>>(ga, gb, ws);
    gk3_cov<<<2, 256, 0, stream>>>(ws);
    gk4_final<<<1, 64, 0, stream>>>(ws, out);
}

// Round 3
// 196.030 us; speedup vs baseline: 1.6788x; 1.1255x over previous
//
#include <hip/hip_runtime.h>
#include <math.h>

#define BATCH 128
#define DIM   8192
#define HW    49
#define PAIRS 2401            // 49*49
#define SLOT  2512            // per-partial slot: 2401 G + 49 nA + 49 nB + pad

// ws float offsets
#define WS_MSE    0
#define WS_VARA   1
#define WS_VARB   2
#define WS_DIAGA  3
#define WS_DIAGB  4
#define WS_S1     5
#define WS_S2     6
#define WS_S3     7
#define WS_S4     8
#define WS_SK2A   9
#define WS_SK2B   10
#define COLS_OFF    16                         // sa,qa,sb,qb: 4*DIM
#define GRAMA_OFF   32784
#define GRAMB_OFF   49168
#define GK2PART_OFF 65552                      // 128 blocks * 16384
#define L1PART_BIG  2162704                    // 1024 blocks * SLOT
#define WS_NEED_FLOATS (L1PART_BIG + 1024 * SLOT)   // 4,734,992 (~19 MB)
#define L1PART_SMALL 65552                     // fallback: 128 batch slots (atomic)

typedef __attribute__((ext_vector_type(8))) short bf16x8;
typedef __attribute__((ext_vector_type(4))) float f32x4;

__device__ __forceinline__ unsigned pk2bf(float lo, float hi) {
    unsigned ulo = __float_as_uint(lo);
    unsigned uhi = __float_as_uint(hi);
    ulo += 0x7FFFu + ((ulo >> 16) & 1u);   // RNE to bf16
    uhi += 0x7FFFu + ((uhi >> 16) & 1u);
    return (ulo >> 16) | (uhi & 0xFFFF0000u);
}
__device__ __forceinline__ float sq4(float4 v) {
    return v.x * v.x + v.y * v.y + v.z * v.z + v.w * v.w;
}

// ---------------------------------------------------------------------------
// L1: per-batch padded 64x64 Gram of 49x8192 features, bf16 MFMA.
// grid = 128 batches * 8 K-splits (K=1024/block), 256 thr (4 waves).
// 2-deep register prefetch pipeline, BK=64/stage, 16 stages:
//   pre: load(0)->A; write(A); load(1)->B; bar
//   t+=2: {load(t+2)->A; PIN; mfma(t); bar; write(B=t+1); bar;
//          load(t+3)->B; PIN; mfma(t+1); bar; write(A=t+2); bar}
//   epi:  mfma(14); bar; write(B=15); bar; mfma(15)
// PIN = sched_barrier(0) keeps loads issued ahead of the MFMA phase.
// LDS 16KB: [2 tensors][64 rows][64 bf16], XOR-swizzle byte^=(row&7)<<4.
// Output: disjoint per-block partial slot (RED) or per-batch atomic (fallback).
// ---------------------------------------------------------------------------
#define L1_SPLIT 8
#define L1_KB   1024
#define L1_BK   64
#define L1_S    (L1_KB / L1_BK)   // 16

#define L1_LOAD(SA, SB, t) do {                                                   \
    _Pragma("unroll") for (int p = 0; p < 4; ++p) {                               \
        if (rb + 16 * p < HW) {                                                   \
            SA[p] = *(const float4*)(gA + (size_t)(t) * L1_BK + (size_t)(p * 16) * DIM); \
            SB[p] = *(const float4*)(gB + (size_t)(t) * L1_BK + (size_t)(p * 16) * DIM); \
        } } } while (0)

#define L1_WRITE(SA, SB) do {                                                     \
    _Pragma("unroll") for (int p = 0; p < 4; ++p) {                               \
        int row_ = rb + 16 * p;                                                   \
        if (row_ < HW) {                                                          \
            int ab_ = ((row_ * 128 + ck * 8) ^ ((row_ & 7) << 4));                \
            *(uint2*)(lds + ab_) =                                                \
                make_uint2(pk2bf(SA[p].x, SA[p].y), pk2bf(SA[p].z, SA[p].w));     \
            *(uint2*)(lds + 8192 + ab_) =                                         \
                make_uint2(pk2bf(SB[p].x, SB[p].y), pk2bf(SB[p].z, SB[p].w));     \
            nA[p] += sq4(SA[p]); nB[p] += sq4(SB[p]);                             \
        } } } while (0)

#define L1_MFMA() do {                                                            \
    _Pragma("unroll") for (int kk2 = 0; kk2 < 128; kk2 += 64) {                   \
        bf16x8 a0 = *(const bf16x8*)(lds + ((r0 * 128 + kk2 + kg16) ^ fsw));      \
        bf16x8 a1 = *(const bf16x8*)(lds + (((r0 + 16) * 128 + kk2 + kg16) ^ fsw)); \
        bf16x8 b0 = *(const bf16x8*)(lds + 8192 + ((c0 * 128 + kk2 + kg16) ^ fsw)); \
        bf16x8 b1 = *(const bf16x8*)(lds + 8192 + (((c0 + 16) * 128 + kk2 + kg16) ^ fsw)); \
        acc00 = __builtin_amdgcn_mfma_f32_16x16x32_bf16(a0, b0, acc00, 0, 0, 0);  \
        acc01 = __builtin_amdgcn_mfma_f32_16x16x32_bf16(a0, b1, acc01, 0, 0, 0);  \
        acc10 = __builtin_amdgcn_mfma_f32_16x16x32_bf16(a1, b0, acc10, 0, 0, 0);  \
        acc11 = __builtin_amdgcn_mfma_f32_16x16x32_bf16(a1, b1, acc11, 0, 0, 0);  \
    } } while (0)

template<bool RED>
__global__ __launch_bounds__(256) void l1_gram(const float* __restrict__ za,
                                               const float* __restrict__ zb,
                                               float* __restrict__ l1part)
{
    __shared__ unsigned char lds[16384];

    const int tid = threadIdx.x;
    const int batch = blockIdx.x >> 3;
    const int ks    = blockIdx.x & 7;
    const float* Ab = za + (size_t)batch * HW * DIM + ks * L1_KB;
    const float* Bb = zb + (size_t)batch * HW * DIM + ks * L1_KB;

    const int ck = tid & 15;          // 16B chunk within 64-float row
    const int rb = tid >> 4;          // base row 0..15 (rows rb+16p)
    const int lane = tid & 63;
    const int wv = tid >> 6;
    const int wr = wv >> 1, wc = wv & 1;
    const int kg = lane >> 4, fr = lane & 15;
    const int kg16 = kg * 16;
    const int fsw = (fr & 7) << 4;
    const int r0 = wr * 32 + fr;
    const int c0 = wc * 32 + fr;

    const float* gA = Ab + (size_t)rb * DIM + ck * 4;
    const float* gB = Bb + (size_t)rb * DIM + ck * 4;

    // zero pad rows 49..63 (never rewritten; swizzle permutes within-row)
    if (tid < 240) {
        int tens = tid / 120, j = tid % 120;
        *(uint4*)(lds + tens * 8192 + (49 + (j >> 3)) * 128 + (j & 7) * 16) =
            make_uint4(0u, 0u, 0u, 0u);
    }

    f32x4 acc00 = {0.f,0.f,0.f,0.f}, acc01 = {0.f,0.f,0.f,0.f};
    f32x4 acc10 = {0.f,0.f,0.f,0.f}, acc11 = {0.f,0.f,0.f,0.f};
    float nA[4] = {0.f,0.f,0.f,0.f}, nB[4] = {0.f,0.f,0.f,0.f};
    float4 A0[4], B0[4], A1[4], B1[4];

    L1_LOAD(A0, B0, 0);
    L1_WRITE(A0, B0);
    L1_LOAD(A1, B1, 1);
    __builtin_amdgcn_sched_barrier(0);
    __syncthreads();                       // stage 0 visible

    for (int t = 0; t + 3 < L1_S; t += 2) {
        L1_LOAD(A0, B0, t + 2);
        __builtin_amdgcn_sched_barrier(0);
        L1_MFMA();                         // stage t
        __syncthreads();
        L1_WRITE(A1, B1);                  // stage t+1
        __syncthreads();
        L1_LOAD(A1, B1, t + 3);
        __builtin_amdgcn_sched_barrier(0);
        L1_MFMA();                         // stage t+1
        __syncthreads();
        L1_WRITE(A0, B0);                  // stage t+2
        __syncthreads();
    }
    L1_MFMA();                             // stage 14
    __syncthreads();
    L1_WRITE(A1, B1);                      // stage 15
    __syncthreads();
    L1_MFMA();                             // stage 15

    float* gout = l1part + (size_t)(RED ? blockIdx.x : batch) * SLOT;

    // row norms: 16 consecutive lanes per row -> shfl tree
#pragma unroll
    for (int p = 0; p < 4; ++p) {
        float vA = nA[p], vB = nB[p];
        vA += __shfl_xor(vA, 1);  vB += __shfl_xor(vB, 1);
        vA += __shfl_xor(vA, 2);  vB += __shfl_xor(vB, 2);
        vA += __shfl_xor(vA, 4);  vB += __shfl_xor(vB, 4);
        vA += __shfl_xor(vA, 8);  vB += __shfl_xor(vB, 8);
        int row = rb + 16 * p;
        if ((tid & 15) == 0 && row < HW) {
            if (RED) { gout[PAIRS + row] = vA; gout[PAIRS + HW + row] = vB; }
            else { atomicAdd(&gout[PAIRS + row], vA); atomicAdd(&gout[PAIRS + HW + row], vB); }
        }
    }

    // Gram writeout: C/D layout col=lane&15, row=(lane>>4)*4+reg
#define L1_WACC(A, sr, sc)                                                        \
    _Pragma("unroll") for (int r = 0; r < 4; ++r) {                               \
        int row_ = wr * 32 + (sr) * 16 + kg * 4 + r;                              \
        int col_ = wc * 32 + (sc) * 16 + fr;                                      \
        if (row_ < HW && col_ < HW) {                                             \
            if (RED) gout[row_ * HW + col_] = A[r];                               \
            else atomicAdd(&gout[row_ * HW + col_], A[r]);                        \
        } }
    L1_WACC(acc00, 0, 0) L1_WACC(acc01, 0, 1) L1_WACC(acc10, 1, 0) L1_WACC(acc11, 1, 1)
#undef L1_WACC
}

// ---------------------------------------------------------------------------
// L2: per-batch matching. RED mode folds the 8-way K-split reduction of the
// l1 partial Grams/norms into the d2f build. Selection logic unchanged.
// ---------------------------------------------------------------------------
template<bool RED>
__global__ __launch_bounds__(256) void l2_match(const float* __restrict__ ga,
                                                const float* __restrict__ gb,
                                                float* __restrict__ ws,
                                                const float* __restrict__ l1part)
{
    __shared__ float d2f[PAIRS];
    __shared__ float d2g[PAIRS];
    __shared__ float nAs[49], nBs[49];
    __shared__ float gax[49], gay[49], gbx[49], gby[49];
    __shared__ float mval[4][49];
    __shared__ int   midx[4][49];

    const int tid = threadIdx.x;
    const int batch = blockIdx.x;
    const float* P0 = l1part + (size_t)batch * (RED ? (8 * SLOT) : SLOT);

    auto rd = [&](int off) -> float {
        if (!RED) return P0[off];
        float s = 0.f;
#pragma unroll
        for (int ss = 0; ss < 8; ++ss) s += P0[ss * SLOT + off];
        return s;
    };

    if (tid < 49) nAs[tid] = rd(PAIRS + tid);
    else if (tid >= 64 && tid < 113) nBs[tid - 64] = rd(PAIRS + 49 + (tid - 64));
    if (tid >= 128 && tid < 177) {
        int i = tid - 128;
        gax[i] = ga[batch * 98 + i * 2];
        gay[i] = ga[batch * 98 + i * 2 + 1];
    } else if (tid >= 192 && tid < 241) {
        int i = tid - 192;
        gbx[i] = gb[batch * 98 + i * 2];
        gby[i] = gb[batch * 98 + i * 2 + 1];
    }
    __syncthreads();
    for (int e = tid; e < PAIRS; e += 256) {
        int i = e / 49, j = e - i * 49;
        d2f[e] = nAs[i] + nBs[j] - 2.0f * rd(e);
        float dx = gax[i] - gbx[j], dy = gay[i] - gby[j];
        d2g[e] = dx * dx + dy * dy;
    }
    __syncthreads();
    const int task = tid >> 6, l = tid & 63;
    if (l < 49) {
        float bv = 3.0e38f; int bi = 0;
        if (task == 0) {
            for (int j = 0; j < 49; ++j) { float v = d2f[l * 49 + j]; if (v < bv) { bv = v; bi = j; } }
        } else if (task == 1) {
            for (int i = 0; i < 49; ++i) { float v = d2f[i * 49 + l]; if (v < bv) { bv = v; bi = i; } }
        } else if (task == 2) {
            for (int j = 0; j < 49; ++j) { float v = d2g[l * 49 + j]; if (v < bv) { bv = v; bi = j; } }
        } else {
            for (int i = 0; i < 49; ++i) { float v = d2g[i * 49 + l]; if (v < bv) { bv = v; bi = i; } }
        }
        mval[task][l] = bv; midx[task][l] = bi;
    }
    __syncthreads();
    if (l < 49) {
        float v = mval[task][l];
        int rank = 0;
        for (int k = 0; k < 49; ++k) {
            float u = mval[task][k];
            rank += (u < v) || (u == v && k < l);   // stable: matches lax.top_k ties
        }
        if (task == 0)      { if (rank < 20) atomicAdd(&ws[WS_S1], v); }
        else if (task == 1) { if (rank < 20) atomicAdd(&ws[WS_S2], v); }
        else if (task == 2) { if (rank < 20) atomicAdd(&ws[WS_S3], d2f[l * 49 + midx[2][l]]); }
        else                { if (rank < 4)  atomicAdd(&ws[WS_S4], d2f[midx[3][l] * 49 + l]); }
    }
}

// ---------------------------------------------------------------------------
// GK2: 128x128 Gram of z_a/z_b, K-split 64 chunks of 128 cols. Also emits the
// per-column sum/sumsq (each block owns disjoint columns -> plain stores),
// replacing the old gk1a column pass. RED: disjoint Gram partials; else atomic.
// ---------------------------------------------------------------------------
template<bool RED>
__global__ __launch_bounds__(256) void gk2_gram(const float* __restrict__ za,
                                                const float* __restrict__ zb,
                                                float* __restrict__ ws,
                                                float* __restrict__ part)
{
    __shared__ float sx[128 * 68];
    const int tid = threadIdx.x;
    const int tensor = blockIdx.x >> 6;
    const int chunk  = blockIdx.x & 63;
    const float* X = (tensor ? zb : za) + chunk * 128;
    const int ty = tid >> 4, tx = tid & 15;
    const int q = tid >> 6, cc = tid & 63;

    float acc[8][8];
#pragma unroll
    for (int r = 0; r < 8; ++r)
#pragma unroll
        for (int c = 0; c < 8; ++c) acc[r][c] = 0.f;
    float colS[2] = {0.f, 0.f}, colQ[2] = {0.f, 0.f};

#pragma unroll
    for (int stage = 0; stage < 2; ++stage) {
        __syncthreads();
        for (int f = tid; f < 128 * 16; f += 256) {
            int row = f >> 4, c4 = f & 15;
            *(float4*)(sx + row * 68 + c4 * 4) =
                *(const float4*)(X + (size_t)row * DIM + stage * 64 + c4 * 4);
        }
        __syncthreads();
        // column stats: thread (q,cc) sums rows [q*32, q*32+32) of col cc
        for (int r = 0; r < 32; ++r) {
            float v = sx[(q * 32 + r) * 68 + cc];
            colS[stage] += v; colQ[stage] += v * v;
        }
        for (int k = 0; k < 64; k += 4) {
            float4 a4[8];
#pragma unroll
            for (int r = 0; r < 8; ++r) a4[r] = *(const float4*)(sx + (ty + 16 * r) * 68 + k);
#pragma unroll
            for (int c = 0; c < 8; ++c) {
                float4 b4 = *(const float4*)(sx + (tx + 16 * c) * 68 + k);
#pragma unroll
                for (int r = 0; r < 8; ++r)
                    acc[r][c] += a4[r].x * b4.x + a4[r].y * b4.y + a4[r].z * b4.z + a4[r].w * b4.w;
            }
        }
    }
    // combine column stats (reuse sx as scratch)
    __syncthreads();
#pragma unroll
    for (int st = 0; st < 2; ++st) {
        sx[tid] = colS[st];
        sx[256 + tid] = colQ[st];
        __syncthreads();
        if (tid < 64) {
            float s  = sx[tid] + sx[64 + tid] + sx[128 + tid] + sx[192 + tid];
            float qq = sx[256 + tid] + sx[320 + tid] + sx[384 + tid] + sx[448 + tid];
            int col = chunk * 128 + st * 64 + tid;
            float* C = ws + COLS_OFF + tensor * 2 * DIM;
            C[col] = s; C[DIM + col] = qq;
        }
        __syncthreads();
    }
    if (RED) {
        float* P = part + (size_t)blockIdx.x * 16384;
#pragma unroll
        for (int r = 0; r < 8; ++r)
#pragma unroll
            for (int c = 0; c < 8; ++c)
                P[(ty + 16 * r) * 128 + (tx + 16 * c)] = acc[r][c];
    } else {
        float* G = ws + (tensor ? GRAMB_OFF : GRAMA_OFF);
#pragma unroll
        for (int r = 0; r < 8; ++r)
#pragma unroll
            for (int c = 0; c < 8; ++c)
                atomicAdd(&G[(ty + 16 * r) * 128 + (tx + 16 * c)], acc[r][c]);
    }
}

__global__ __launch_bounds__(256) void gk2_reduce(float* __restrict__ ws)
{
    const int g = blockIdx.x * 256 + threadIdx.x;   // 0..32767
    const int tensor = g >> 14;
    const int e = g & 16383;
    const float* P = ws + GK2PART_OFF + (size_t)tensor * 64 * 16384;
    float s = 0.f;
    for (int c = 0; c < 64; ++c) s += P[(size_t)c * 16384 + e];
    ws[(tensor ? GRAMB_OFF : GRAMA_OFF) + e] = s;
}

// ---------------------------------------------------------------------------
// GK1m: global MSE only (column stats now come from gk2). 65536 threads x 16B.
// ---------------------------------------------------------------------------
__global__ __launch_bounds__(256) void gk1_mse(const float* __restrict__ za,
                                               const float* __restrict__ zb,
                                               float* __restrict__ ws)
{
    const size_t i0 = ((size_t)blockIdx.x * 256 + threadIdx.x) * 4;
    float ms = 0.f;
#pragma unroll
    for (int it = 0; it < 4; ++it) {
        size_t idx = i0 + (size_t)it * 262144;
        float4 a = *(const float4*)(za + idx);
        float4 b = *(const float4*)(zb + idx);
        float dx = a.x - b.x, dy = a.y - b.y, dz = a.z - b.z, dw = a.w - b.w;
        ms += dx * dx + dy * dy + dz * dz + dw * dw;
    }
    for (int o = 32; o; o >>= 1) ms += __shfl_xor(ms, o);
    if ((threadIdx.x & 63) == 0) atomicAdd(&ws[WS_MSE], ms);
}

// GK1b: per-column std/relu/diag from COLS arrays -> scalars.
__global__ __launch_bounds__(256) void gk1b(float* __restrict__ ws)
{
    const int col = blockIdx.x * 256 + threadIdx.x;
    float sa = ws[COLS_OFF + col];
    float qa = ws[COLS_OFF + DIM + col];
    float sb = ws[COLS_OFF + 2 * DIM + col];
    float qb = ws[COLS_OFF + 3 * DIM + col];
    float sA = qa - sa * sa * (1.0f / BATCH);
    float sB = qb - sb * sb * (1.0f / BATCH);
    float rA = fmaxf(0.f, 1.f - sqrtf(sA * (1.0f / (BATCH - 1)) + 1e-4f));
    float rB = fmaxf(0.f, 1.f - sqrtf(sB * (1.0f / (BATCH - 1)) + 1e-4f));
    float dA = sA * sA, dB = sB * sB;
    for (int o = 32; o; o >>= 1) {
        rA += __shfl_xor(rA, o);
        rB += __shfl_xor(rB, o);
        dA += __shfl_xor(dA, o);
        dB += __shfl_xor(dB, o);
    }
    if ((threadIdx.x & 63) == 0) {
        atomicAdd(&ws[WS_VARA],  rA);
        atomicAdd(&ws[WS_VARB],  rB);
        atomicAdd(&ws[WS_DIAGA], dA);
        atomicAdd(&ws[WS_DIAGB], dB);
    }
}

// ---------------------------------------------------------------------------
// GK3: ||K||_F^2 from the Gram. K = G - (r_i+r_j)/n + S/n^2.
// ---------------------------------------------------------------------------
__global__ __launch_bounds__(256) void gk3_cov(float* __restrict__ ws)
{
    __shared__ float r[128];
    __shared__ float sS;
    __shared__ float wrd[4];
    const int tid = threadIdx.x;
    const float* G = ws + (blockIdx.x ? GRAMB_OFF : GRAMA_OFF);
    if (tid < 128) {
        float s0 = 0.f, s1 = 0.f, s2 = 0.f, s3 = 0.f;
        for (int k = 0; k < 128; k += 4) {
            s0 += G[(k + 0) * 128 + tid];
            s1 += G[(k + 1) * 128 + tid];
            s2 += G[(k + 2) * 128 + tid];
            s3 += G[(k + 3) * 128 + tid];
        }
        r[tid] = (s0 + s1) + (s2 + s3);
    }
    __syncthreads();
    if (tid < 64) {
        float t = r[tid] + r[tid + 64];
        for (int o = 32; o; o >>= 1) t += __shfl_xor(t, o);
        if (tid == 0) sS = t;
    }
    __syncthreads();
    const float S = sS;
    float sk = 0.f;
    for (int e = tid; e < 16384; e += 256) {
        float K = G[e] - (r[e >> 7] + r[e & 127]) * (1.0f / 128.0f) + S * (1.0f / 16384.0f);
        sk += K * K;
    }
    for (int o = 32; o; o >>= 1) sk += __shfl_xor(sk, o);
    if ((tid & 63) == 0) wrd[tid >> 6] = sk;
    __syncthreads();
    if (tid == 0)
        ws[blockIdx.x ? WS_SK2B : WS_SK2A] = wrd[0] + wrd[1] + wrd[2] + wrd[3];
}

// ---------------------------------------------------------------------------
// GK4: final scalar assembly.
// ---------------------------------------------------------------------------
__global__ void gk4_final(const float* __restrict__ ws, float* __restrict__ out)
{
    if (threadIdx.x == 0) {
        float inv_g = ws[WS_MSE] * (1.0f / ((float)BATCH * (float)DIM));
        float varl  = 0.5f * (ws[WS_VARA] + ws[WS_VARB]) * (1.0f / (float)DIM);
        float cov   = (ws[WS_SK2A] - ws[WS_DIAGA] + ws[WS_SK2B] - ws[WS_DIAGB])
                      * (1.0f / (127.0f * 127.0f * (float)DIM));
        float gl = 25.0f * inv_g + 25.0f * varl + cov;
        float m20 = (float)BATCH * 20.0f * (float)DIM;
        float m4  = (float)BATCH * 4.0f  * (float)DIM;
        float invl = 0.5f * (ws[WS_S1] + ws[WS_S2] + ws[WS_S3]) / m20
                   + 0.5f * ws[WS_S4] / m4;
        out[0] = 0.25f * gl + 0.75f * (25.0f * invl);
    }
}

extern "C" void kernel_launch(void* const* d_in, const int* in_sizes, int n_in,
                              void* d_out, int out_size, void* d_ws, size_t ws_size,
                              hipStream_t stream)
{
    (void)in_sizes; (void)n_in; (void)out_size;
    const float* z_a = (const float*)d_in[0];
    const float* z_b = (const float*)d_in[1];
    const float* zla = (const float*)d_in[2];
    const float* zlb = (const float*)d_in[3];
    const float* ga  = (const float*)d_in[4];
    const float* gb  = (const float*)d_in[5];
    float* ws  = (float*)d_ws;
    float* out = (float*)d_out;

    const bool big = ws_size >= (size_t)WS_NEED_FLOATS * sizeof(float);

    if (big) {
        // only the accumulated scalars need zeroing; everything else is
        // fully overwritten (COLS by gk2 stores, GRAM by gk2_reduce,
        // partials by their producers)
        hipMemsetAsync(d_ws, 0, 16 * sizeof(float), stream);
        l1_gram<true><<<BATCH * L1_SPLIT, 256, 0, stream>>>(zla, zlb, ws + L1PART_BIG);
        gk2_gram<true><<<128, 256, 0, stream>>>(z_a, z_b, ws, ws + GK2PART_OFF);
        gk2_reduce<<<128, 256, 0, stream>>>(ws);
        gk1_mse<<<256, 256, 0, stream>>>(z_a, z_b, ws);
        gk1b<<<DIM / 256, 256, 0, stream>>>(ws);
        l2_match<true><<<BATCH, 256, 0, stream>>>(ga, gb, ws, ws + L1PART_BIG);
        gk3_cov<<<2, 256, 0, stream>>>(ws);
        gk4_final<<<1, 64, 0, stream>>>(ws, out);
    } else {
        // fallback: atomic accumulation, small footprint (~1.55 MB)
        hipMemsetAsync(d_ws, 0, (size_t)(L1PART_SMALL + BATCH * SLOT) * sizeof(float), stream);
        l1_gram<false><<<BATCH * L1_SPLIT, 256, 0, stream>>>(zla, zlb, ws + L1PART_SMALL);
        gk2_gram<false><<<128, 256, 0, stream>>>(z_a, z_b, ws, ws);
        gk1_mse<<<256, 256, 0, stream>>>(z_a, z_b, ws);
        gk1b<<<DIM / 256, 256, 0, stream>>>(ws);
        l2_match<false><<<BATCH, 256, 0, stream>>>(ga, gb, ws, ws + L1PART_SMALL);
        gk3_cov<<<2, 256, 0, stream>>>(ws);
        gk4_final<<<1, 64, 0, stream>>>(ws, out);
    }
}